// Round 11
// baseline (147.549 us; speedup 1.0000x reference)
//
#include <hip/hip_runtime.h>
#include <math.h>

#define Bb 2
#define Ll 2048
#define Dm 1024
#define Ns 16
#define Rr 64
#define Ee 96          // DT_RANK + 2*D_STATE
#define BLK (Bb*Ll)    // 4096 rows
#define NTHR 256
#define LOG2E 1.4426950408889634f
#define LN2   0.6931471805599453f

typedef __attribute__((ext_vector_type(8))) short bf16x8;
typedef __attribute__((ext_vector_type(4))) float f32x4;

__device__ inline float ex2(float x) {
#if __has_builtin(__builtin_amdgcn_exp2f)
    return __builtin_amdgcn_exp2f(x);
#else
    return exp2f(x);
#endif
}
__device__ inline float lg2(float x) {
#if __has_builtin(__builtin_amdgcn_logf)
    return __builtin_amdgcn_logf(x);
#else
    return log2f(x);
#endif
}
__device__ inline float softplus_f(float z) {
    float e = ex2(-fabsf(z) * LOG2E);
    return fmaxf(z, 0.f) + lg2(1.f + e) * LN2;
}

// f32 -> bf16 with round-to-nearest-even
__device__ inline unsigned short f2bf(float f) {
    union { float f; unsigned u; } v; v.f = f;
    unsigned u = v.u + 0x7fffu + ((v.u >> 16) & 1u);
    return (unsigned short)(u >> 16);
}
__device__ inline uint2 pack4(float a, float b, float c, float d) {
    unsigned u0 = ((unsigned)f2bf(b) << 16) | f2bf(a);
    unsigned u1 = ((unsigned)f2bf(d) << 16) | f2bf(c);
    return make_uint2(u0, u1);
}

// ========== Kernel 1: xp += partial  (bf16 MFMA; K-split blocks atomicAdd into xp) ==========
// grid = 256 m-tiles x 8 K-slices = 2048 blocks. Per block: stage A(16x128)+B(96x128)
// bf16, 4 waves each MFMA their K-quarter (6 MFMA), LDS-reduce, atomicAdd 16x96 tile.
// xp is zeroed by a captured hipMemsetAsync before launch. Replaces xproj+prep.
__global__ void __launch_bounds__(NTHR, 4)
k_xproj(const float* __restrict__ x, const float* __restrict__ xw,
        float* __restrict__ xp) {
    __shared__ __align__(16) short sm[16*128 + 96*128];   // A | B ; f32 reduce alias
    int tid = threadIdx.x, lane = tid & 63, wid = tid >> 6;
    int bx = blockIdx.x;
    int ks = bx & 7, mt = bx >> 3;
    int i0 = mt * 16;
    int kb = ks * 128;
    short* sA = sm;
    short* sB = sm + 16*128;

#pragma unroll
    for (int i = 0; i < 2; ++i) {
        int idx = tid + i * 256;
        int r = idx >> 5, c4 = idx & 31;
        float4 v = *(const float4*)(x + (size_t)(i0 + r) * Dm + kb + c4 * 4);
        int unit = (c4 >> 1) ^ (r & 7);
        *(uint2*)(sA + r * 128 + unit * 8 + (c4 & 1) * 4) = pack4(v.x, v.y, v.z, v.w);
    }
#pragma unroll
    for (int i = 0; i < 12; ++i) {
        int idx = tid + i * 256;
        int r = idx >> 5, c4 = idx & 31;
        float4 v = *(const float4*)(xw + (size_t)r * Dm + kb + c4 * 4);
        int unit = (c4 >> 1) ^ (r & 7);
        *(uint2*)(sB + r * 128 + unit * 8 + (c4 & 1) * 4) = pack4(v.x, v.y, v.z, v.w);
    }
    __syncthreads();

    f32x4 acc[6];
#pragma unroll
    for (int t = 0; t < 6; ++t) acc[t] = (f32x4)0.f;
    int ra = lane & 15;
    int g = wid * 4 + (lane >> 4);                 // 0..15
    bf16x8 a = *(bf16x8*)(sA + ra * 128 + ((g ^ (ra & 7)) << 3));
#pragma unroll
    for (int nt = 0; nt < 6; ++nt) {
        int br = nt * 16 + (lane & 15);
        bf16x8 b = *(bf16x8*)(sB + br * 128 + ((g ^ (br & 7)) << 3));
        acc[nt] = __builtin_amdgcn_mfma_f32_16x16x32_bf16(a, b, acc[nt], 0, 0, 0);
    }
    __syncthreads();

    float* rp = (float*)sm;
#pragma unroll
    for (int nt = 0; nt < 6; ++nt)
#pragma unroll
        for (int j = 0; j < 4; ++j) {
            int r = ((lane >> 4) << 2) + j;
            int c = nt * 16 + (lane & 15);
            rp[wid * 1536 + r * 96 + c] = acc[nt][j];
        }
    __syncthreads();
#pragma unroll
    for (int o = 0; o < 6; ++o) {
        int idx = o * 256 + tid;
        float s = rp[idx] + rp[1536 + idx] + rp[3072 + idx] + rp[4608 + idx];
        int r = idx / 96, c = idx - r * 96;
        atomicAdd(xp + (size_t)(i0 + r) * Ee + c, s);
    }
}

// ========== Kernel 2: delta = softplus(xp[:, :64] . dtw^T + dtb)  (bf16 MFMA; R9 verbatim) ==========
__global__ void __launch_bounds__(NTHR)
k_delta(const float* __restrict__ xp, const float* __restrict__ dtw,
        const float* __restrict__ dtb, float* __restrict__ delta) {
    __shared__ __align__(16) short sA[128 * 64];
    __shared__ __align__(16) short sB[64 * 64];
    int tid = threadIdx.x, lane = tid & 63, wid = tid >> 6;
    int nt16 = blockIdx.x & 15, mt = blockIdx.x >> 4;
    int i0 = mt * 128, j0 = nt16 * 64;

#pragma unroll
    for (int i = 0; i < 8; ++i) {
        int idx = tid + i * 256;
        int r = idx >> 4, c4 = idx & 15;
        float4 v = *(const float4*)(xp + (size_t)(i0 + r) * Ee + c4 * 4);
        int unit = (c4 >> 1) ^ (r & 7);
        *(uint2*)(sA + r * 64 + unit * 8 + (c4 & 1) * 4) = pack4(v.x, v.y, v.z, v.w);
    }
#pragma unroll
    for (int i = 0; i < 4; ++i) {
        int idx = tid + i * 256;
        int r = idx >> 4, c4 = idx & 15;
        float4 v = *(const float4*)(dtw + (size_t)(j0 + r) * Rr + c4 * 4);
        int unit = (c4 >> 1) ^ (r & 7);
        *(uint2*)(sB + r * 64 + unit * 8 + (c4 & 1) * 4) = pack4(v.x, v.y, v.z, v.w);
    }
    __syncthreads();

    f32x4 acc[2][4];
#pragma unroll
    for (int m = 0; m < 2; ++m)
#pragma unroll
        for (int nt = 0; nt < 4; ++nt) acc[m][nt] = (f32x4)0.f;
    int R = wid * 32;
    int r0 = R + (lane & 15), r1 = R + 16 + (lane & 15);
#pragma unroll
    for (int ks = 0; ks < 2; ++ks) {
        int g = ks * 4 + (lane >> 4);
        bf16x8 a0 = *(bf16x8*)(sA + r0 * 64 + ((g ^ (r0 & 7)) << 3));
        bf16x8 a1 = *(bf16x8*)(sA + r1 * 64 + ((g ^ (r1 & 7)) << 3));
#pragma unroll
        for (int nt = 0; nt < 4; ++nt) {
            int br = nt * 16 + (lane & 15);
            bf16x8 b = *(bf16x8*)(sB + br * 64 + ((g ^ (br & 7)) << 3));
            acc[0][nt] = __builtin_amdgcn_mfma_f32_16x16x32_bf16(a0, b, acc[0][nt], 0, 0, 0);
            acc[1][nt] = __builtin_amdgcn_mfma_f32_16x16x32_bf16(a1, b, acc[1][nt], 0, 0, 0);
        }
    }
#pragma unroll
    for (int nt = 0; nt < 4; ++nt) {
        int col = j0 + nt * 16 + (lane & 15);
        float bias = dtb[col];
#pragma unroll
        for (int m = 0; m < 2; ++m)
#pragma unroll
            for (int j = 0; j < 4; ++j) {
                int row = i0 + R + m * 16 + ((lane >> 4) << 2) + j;
                delta[(size_t)row * Dm + col] = softplus_f(acc[m][nt][j] + bias);
            }
    }
}

// ---- helper: load A row, pre-scaled by log2(e), into regs ----
__device__ inline void load_a2(const float* __restrict__ A_log, int d, float* a2) {
    const float4* Ap = (const float4*)(A_log + (size_t)d * Ns);
    float4 a0 = Ap[0], a1 = Ap[1], a2v = Ap[2], a3 = Ap[3];
    float tmp[Ns] = {a0.x,a0.y,a0.z,a0.w, a1.x,a1.y,a1.z,a1.w,
                     a2v.x,a2v.y,a2v.z,a2v.w, a3.x,a3.y,a3.z,a3.w};
#pragma unroll
    for (int n = 0; n < Ns; ++n) a2[n] = -__expf(tmp[n]) * LOG2E;
}

// ========== Kernel 3: per-chunk local scan (h0=0) -> Ec, Sc  (R9 + unroll 8) ==========
template<int CHv>
__global__ void __launch_bounds__(NTHR)
k_scan_part(const float* __restrict__ delta, const float* __restrict__ x,
            const float* __restrict__ xp, const float* __restrict__ A_log,
            float* __restrict__ Ec, float* __restrict__ Sc) {
    constexpr int CLv = Ll / CHv;
    int bx = blockIdx.x;
    int dblk = bx & 3, chunk = (bx >> 2) & (CHv - 1), b = bx >> 2 >> __builtin_ctz(CHv);
    int tid = threadIdx.x;
    int d = dblk * 256 + tid;
    int row0 = b * Ll + chunk * CLv;

    float a2[Ns], h[Ns];
    load_a2(A_log, d, a2);
#pragma unroll
    for (int n = 0; n < Ns; ++n) h[n] = 0.f;
    float sd = 0.f;

#pragma unroll 8
    for (int t = 0; t < CLv; ++t) {
        size_t row = (size_t)(row0 + t);
        float dl = delta[row * Dm + d];
        float xv = x[row * Dm + d];
        const float* bp = xp + row * Ee + Rr;
        float4 B0 = *(const float4*)(bp + 0),  B1 = *(const float4*)(bp + 4);
        float4 B2 = *(const float4*)(bp + 8),  B3 = *(const float4*)(bp + 12);
        float Bv[Ns] = {B0.x,B0.y,B0.z,B0.w, B1.x,B1.y,B1.z,B1.w,
                        B2.x,B2.y,B2.z,B2.w, B3.x,B3.y,B3.z,B3.w};
        float dx = dl * xv;
        sd += dl;
#pragma unroll
        for (int n = 0; n < Ns; ++n)
            h[n] = fmaf(ex2(dl * a2[n]), h[n], dx * Bv[n]);
    }
    size_t base = ((size_t)b * CHv + chunk) * Dm + d;
    float4* Ep = (float4*)(Ec + base * Ns);
    Ep[0] = make_float4(h[0],  h[1],  h[2],  h[3]);
    Ep[1] = make_float4(h[4],  h[5],  h[6],  h[7]);
    Ep[2] = make_float4(h[8],  h[9],  h[10], h[11]);
    Ep[3] = make_float4(h[12], h[13], h[14], h[15]);
    Sc[base] = sd;
}

// ========== Kernel 4a: within-group combine (R9 verbatim) ==========
template<int CHv, int G>
__global__ void __launch_bounds__(NTHR)
k_comb1(const float* __restrict__ Ec, const float* __restrict__ Sc,
        const float* __restrict__ A_log, float* __restrict__ Hloc,
        float* __restrict__ Spre, float* __restrict__ Eg, float* __restrict__ Sg) {
    constexpr int CPG = CHv / G;
    int gid = blockIdx.x * NTHR + threadIdx.x;   // Bb*G*Dm*Ns = 262144
    int n = gid & (Ns - 1);
    int d = (gid >> 4) & (Dm - 1);
    int g = (gid >> 14) & (G - 1);
    int b = gid >> 17;
    float a2 = -__expf(A_log[d * Ns + n]) * LOG2E;
    float h = 0.f, S = 0.f;
#pragma unroll
    for (int j = 0; j < CPG; ++j) {
        size_t base = ((size_t)b * CHv + g * CPG + j) * Dm + d;
        float e  = Ec[base * Ns + n];
        float sc = Sc[base];
        Hloc[base * Ns + n] = h;
        if (n == 0) Spre[base] = S;
        h = fmaf(ex2(a2 * sc), h, e);
        S += sc;
    }
    size_t gb = ((size_t)b * G + g) * Dm + d;
    Eg[gb * Ns + n] = h;
    if (n == 0) Sg[gb] = S;
}

// ========== Kernel 4b: across-group combine (R9 verbatim) ==========
template<int G>
__global__ void __launch_bounds__(NTHR)
k_comb2(const float* __restrict__ Eg, const float* __restrict__ Sg,
        const float* __restrict__ A_log, float* __restrict__ Hg) {
    int gid = blockIdx.x * NTHR + threadIdx.x;   // Bb*Dm*Ns = 32768
    int n = gid & (Ns - 1);
    int d = (gid >> 4) & (Dm - 1);
    int b = gid >> 14;
    float a2 = -__expf(A_log[d * Ns + n]) * LOG2E;
    float h = 0.f;
#pragma unroll
    for (int g = 0; g < G; ++g) {
        size_t gb = ((size_t)b * G + g) * Dm + d;
        Hg[gb * Ns + n] = h;
        h = fmaf(ex2(a2 * Sg[gb]), h, Eg[gb * Ns + n]);
    }
}

// ========== Kernel 5: full scan; h_in = Hloc + exp2(a2*Spre)*Hg  (R9 + unroll 8) ==========
template<int CHv, int G>
__global__ void __launch_bounds__(NTHR)
k_scan_full(const float* __restrict__ delta, const float* __restrict__ x,
            const float* __restrict__ xp, const float* __restrict__ A_log,
            const float* __restrict__ Dp, const float* __restrict__ Hloc,
            const float* __restrict__ Spre, const float* __restrict__ Hg,
            float* __restrict__ out) {
    constexpr int CLv = Ll / CHv;
    constexpr int CPG = CHv / G;
    int bx = blockIdx.x;
    int dblk = bx & 3, chunk = (bx >> 2) & (CHv - 1), b = bx >> 2 >> __builtin_ctz(CHv);
    int tid = threadIdx.x;
    int d = dblk * 256 + tid;
    int row0 = b * Ll + chunk * CLv;

    float a2[Ns], h[Ns];
    load_a2(A_log, d, a2);
    size_t base = ((size_t)b * CHv + chunk) * Dm + d;
    size_t gb   = ((size_t)b * G + chunk / CPG) * Dm + d;
    {
        float sp = Spre[base];
        const float4* Hl = (const float4*)(Hloc + base * Ns);
        const float4* Hp = (const float4*)(Hg + gb * Ns);
        float4 l0 = Hl[0], l1 = Hl[1], l2 = Hl[2], l3 = Hl[3];
        float4 g0 = Hp[0], g1 = Hp[1], g2 = Hp[2], g3 = Hp[3];
        float lv[Ns] = {l0.x,l0.y,l0.z,l0.w, l1.x,l1.y,l1.z,l1.w,
                        l2.x,l2.y,l2.z,l2.w, l3.x,l3.y,l3.z,l3.w};
        float gv[Ns] = {g0.x,g0.y,g0.z,g0.w, g1.x,g1.y,g1.z,g1.w,
                        g2.x,g2.y,g2.z,g2.w, g3.x,g3.y,g3.z,g3.w};
#pragma unroll
        for (int n = 0; n < Ns; ++n) h[n] = fmaf(ex2(a2[n] * sp), gv[n], lv[n]);
    }
    float Dval = Dp[d];

#pragma unroll 8
    for (int t = 0; t < CLv; ++t) {
        size_t row = (size_t)(row0 + t);
        float dl = delta[row * Dm + d];
        float xv = x[row * Dm + d];
        const float* bp = xp + row * Ee + Rr;
        float4 B0 = *(const float4*)(bp + 0),  B1 = *(const float4*)(bp + 4);
        float4 B2 = *(const float4*)(bp + 8),  B3 = *(const float4*)(bp + 12);
        float4 C0 = *(const float4*)(bp + 16), C1 = *(const float4*)(bp + 20);
        float4 C2 = *(const float4*)(bp + 24), C3 = *(const float4*)(bp + 28);
        float Bv[Ns] = {B0.x,B0.y,B0.z,B0.w, B1.x,B1.y,B1.z,B1.w,
                        B2.x,B2.y,B2.z,B2.w, B3.x,B3.y,B3.z,B3.w};
        float Cv[Ns] = {C0.x,C0.y,C0.z,C0.w, C1.x,C1.y,C1.z,C1.w,
                        C2.x,C2.y,C2.z,C2.w, C3.x,C3.y,C3.z,C3.w};
        float dx = dl * xv;
        float ya[4] = {0.f, 0.f, 0.f, 0.f};
#pragma unroll
        for (int n = 0; n < Ns; ++n) {
            h[n] = fmaf(ex2(dl * a2[n]), h[n], dx * Bv[n]);
            ya[n & 3] = fmaf(h[n], Cv[n], ya[n & 3]);
        }
        out[row * Dm + d] = fmaf(xv, Dval, (ya[0] + ya[1]) + (ya[2] + ya[3]));
    }
}

extern "C" void kernel_launch(void* const* d_in, const int* in_sizes, int n_in,
                              void* d_out, int out_size, void* d_ws, size_t ws_size,
                              hipStream_t stream) {
    const float* x     = (const float*)d_in[0];
    const float* A_log = (const float*)d_in[1];
    const float* Dp    = (const float*)d_in[2];
    const float* xw    = (const float*)d_in[3];
    const float* dtw   = (const float*)d_in[4];
    const float* dtb   = (const float*)d_in[5];
    float* out = (float*)d_out;
    float* ws  = (float*)d_ws;

    // layout (floats):
    //   xp    : 393216   (zeroed each launch; k_xproj atomically accumulates)
    //   delta : 4194304
    //   S3    : Ec | Sc | Hloc | Spre | Eg | Sg | Hg  (CH=64: ~5.0M floats)
    float* xp    = ws;
    float* delta = xp + 393216;
    float* S3    = delta + 4194304;

    hipMemsetAsync(xp, 0, (size_t)393216 * sizeof(float), stream);
    k_xproj<<<dim3(2048), dim3(NTHR), 0, stream>>>(x, xw, xp);
    k_delta<<<dim3(512),  dim3(NTHR), 0, stream>>>(xp, dtw, dtb, delta);

    constexpr int G = 8;
    constexpr int CHv = 64;
    float* Ec   = S3;
    float* Sc   = Ec   + (size_t)Bb*CHv*Dm*Ns;
    float* Hloc = Sc   + (size_t)Bb*CHv*Dm;
    float* Spre = Hloc + (size_t)Bb*CHv*Dm*Ns;
    float* Eg   = Spre + (size_t)Bb*CHv*Dm;
    float* Sg   = Eg   + (size_t)Bb*G*Dm*Ns;
    float* Hg   = Sg   + (size_t)Bb*G*Dm;

    k_scan_part<CHv>  <<<dim3(Bb*CHv*4), dim3(NTHR), 0, stream>>>(delta, x, xp, A_log, Ec, Sc);
    k_comb1<CHv, G>   <<<dim3(Bb*G*Dm*Ns/NTHR), dim3(NTHR), 0, stream>>>(Ec, Sc, A_log, Hloc, Spre, Eg, Sg);
    k_comb2<G>        <<<dim3(Bb*Dm*Ns/NTHR), dim3(NTHR), 0, stream>>>(Eg, Sg, A_log, Hg);
    k_scan_full<CHv,G><<<dim3(Bb*CHv*4), dim3(NTHR), 0, stream>>>(delta, x, xp, A_log, Dp, Hloc, Spre, Hg, out);
}

// Round 12
// 137.361 us; speedup vs baseline: 1.0742x; 1.0742x over previous
//
#include <hip/hip_runtime.h>
#include <math.h>

#define Bb 2
#define Ll 2048
#define Dm 1024
#define Ns 16
#define Rr 64
#define Ee 96          // DT_RANK + 2*D_STATE
#define XPS 8          // K-splits for xproj GEMM (K-slice = 128)
#define BLK (Bb*Ll)    // 4096 rows
#define NTHR 256
#define LOG2E 1.4426950408889634f
#define LN2   0.6931471805599453f

typedef __attribute__((ext_vector_type(8))) short bf16x8;
typedef __attribute__((ext_vector_type(4))) float f32x4;

__device__ inline float ex2(float x) {
#if __has_builtin(__builtin_amdgcn_exp2f)
    return __builtin_amdgcn_exp2f(x);
#else
    return exp2f(x);
#endif
}
__device__ inline float lg2(float x) {
#if __has_builtin(__builtin_amdgcn_logf)
    return __builtin_amdgcn_logf(x);
#else
    return log2f(x);
#endif
}
__device__ inline float softplus_f(float z) {
    float e = ex2(-fabsf(z) * LOG2E);
    return fmaxf(z, 0.f) + lg2(1.f + e) * LN2;
}

// f32 -> bf16 with round-to-nearest-even
__device__ inline unsigned short f2bf(float f) {
    union { float f; unsigned u; } v; v.f = f;
    unsigned u = v.u + 0x7fffu + ((v.u >> 16) & 1u);
    return (unsigned short)(u >> 16);
}
__device__ inline uint2 pack4(float a, float b, float c, float d) {
    unsigned u0 = ((unsigned)f2bf(b) << 16) | f2bf(a);
    unsigned u1 = ((unsigned)f2bf(d) << 16) | f2bf(c);
    return make_uint2(u0, u1);
}

// ========== Kernel 1: xp_part[ks][bl][e]  (bf16 MFMA; R9 verbatim) ==========
__global__ void __launch_bounds__(NTHR, 4)
k_xproj(const float* __restrict__ x, const float* __restrict__ xw,
        float* __restrict__ xp_part) {
    __shared__ __align__(16) short sm[16*128 + 96*128];   // A | B ; f32 reduce alias
    int tid = threadIdx.x, lane = tid & 63, wid = tid >> 6;
    int bx = blockIdx.x;
    int ks = bx & 7, mt = bx >> 3;
    int i0 = mt * 16;
    int kb = ks * 128;
    short* sA = sm;
    short* sB = sm + 16*128;

#pragma unroll
    for (int i = 0; i < 2; ++i) {
        int idx = tid + i * 256;
        int r = idx >> 5, c4 = idx & 31;
        float4 v = *(const float4*)(x + (size_t)(i0 + r) * Dm + kb + c4 * 4);
        int unit = (c4 >> 1) ^ (r & 7);
        *(uint2*)(sA + r * 128 + unit * 8 + (c4 & 1) * 4) = pack4(v.x, v.y, v.z, v.w);
    }
#pragma unroll
    for (int i = 0; i < 12; ++i) {
        int idx = tid + i * 256;
        int r = idx >> 5, c4 = idx & 31;
        float4 v = *(const float4*)(xw + (size_t)r * Dm + kb + c4 * 4);
        int unit = (c4 >> 1) ^ (r & 7);
        *(uint2*)(sB + r * 128 + unit * 8 + (c4 & 1) * 4) = pack4(v.x, v.y, v.z, v.w);
    }
    __syncthreads();

    f32x4 acc[6];
#pragma unroll
    for (int t = 0; t < 6; ++t) acc[t] = (f32x4)0.f;
    int ra = lane & 15;
    int g = wid * 4 + (lane >> 4);                 // 0..15
    bf16x8 a = *(bf16x8*)(sA + ra * 128 + ((g ^ (ra & 7)) << 3));
#pragma unroll
    for (int nt = 0; nt < 6; ++nt) {
        int br = nt * 16 + (lane & 15);
        bf16x8 b = *(bf16x8*)(sB + br * 128 + ((g ^ (br & 7)) << 3));
        acc[nt] = __builtin_amdgcn_mfma_f32_16x16x32_bf16(a, b, acc[nt], 0, 0, 0);
    }
    __syncthreads();

    float* rp = (float*)sm;
#pragma unroll
    for (int nt = 0; nt < 6; ++nt)
#pragma unroll
        for (int j = 0; j < 4; ++j) {
            int r = ((lane >> 4) << 2) + j;
            int c = nt * 16 + (lane & 15);
            rp[wid * 1536 + r * 96 + c] = acc[nt][j];
        }
    __syncthreads();
#pragma unroll
    for (int o = 0; o < 6; ++o) {
        int idx = o * 256 + tid;
        float s = rp[idx] + rp[1536 + idx] + rp[3072 + idx] + rp[4608 + idx];
        int r = idx / 96, c = idx - r * 96;
        xp_part[((size_t)ks * BLK + (i0 + r)) * Ee + c] = s;
    }
}

// ========== Kernel 2: reduce K-splits -> xp (verbatim) ==========
__global__ void __launch_bounds__(NTHR)
k_prep(const float* __restrict__ xp_part, float* __restrict__ xp) {
    int g = blockIdx.x * NTHR + threadIdx.x;    // 98304 float4s
    const float4* p = (const float4*)xp_part;
    float4 s = p[g];
#pragma unroll
    for (int i = 1; i < XPS; ++i) {
        float4 v = p[(size_t)i * (BLK * Ee / 4) + g];
        s.x += v.x; s.y += v.y; s.z += v.z; s.w += v.w;
    }
    ((float4*)xp)[g] = s;
}

// ========== Kernel 3: delta = softplus(xp[:, :64] . dtw^T + dtb)  (bf16 MFMA; R9 verbatim) ==========
__global__ void __launch_bounds__(NTHR)
k_delta(const float* __restrict__ xp, const float* __restrict__ dtw,
        const float* __restrict__ dtb, float* __restrict__ delta) {
    __shared__ __align__(16) short sA[128 * 64];
    __shared__ __align__(16) short sB[64 * 64];
    int tid = threadIdx.x, lane = tid & 63, wid = tid >> 6;
    int nt16 = blockIdx.x & 15, mt = blockIdx.x >> 4;
    int i0 = mt * 128, j0 = nt16 * 64;

#pragma unroll
    for (int i = 0; i < 8; ++i) {
        int idx = tid + i * 256;
        int r = idx >> 4, c4 = idx & 15;
        float4 v = *(const float4*)(xp + (size_t)(i0 + r) * Ee + c4 * 4);
        int unit = (c4 >> 1) ^ (r & 7);
        *(uint2*)(sA + r * 64 + unit * 8 + (c4 & 1) * 4) = pack4(v.x, v.y, v.z, v.w);
    }
#pragma unroll
    for (int i = 0; i < 4; ++i) {
        int idx = tid + i * 256;
        int r = idx >> 4, c4 = idx & 15;
        float4 v = *(const float4*)(dtw + (size_t)(j0 + r) * Rr + c4 * 4);
        int unit = (c4 >> 1) ^ (r & 7);
        *(uint2*)(sB + r * 64 + unit * 8 + (c4 & 1) * 4) = pack4(v.x, v.y, v.z, v.w);
    }
    __syncthreads();

    f32x4 acc[2][4];
#pragma unroll
    for (int m = 0; m < 2; ++m)
#pragma unroll
        for (int nt = 0; nt < 4; ++nt) acc[m][nt] = (f32x4)0.f;
    int R = wid * 32;
    int r0 = R + (lane & 15), r1 = R + 16 + (lane & 15);
#pragma unroll
    for (int ks = 0; ks < 2; ++ks) {
        int g = ks * 4 + (lane >> 4);
        bf16x8 a0 = *(bf16x8*)(sA + r0 * 64 + ((g ^ (r0 & 7)) << 3));
        bf16x8 a1 = *(bf16x8*)(sA + r1 * 64 + ((g ^ (r1 & 7)) << 3));
#pragma unroll
        for (int nt = 0; nt < 4; ++nt) {
            int br = nt * 16 + (lane & 15);
            bf16x8 b = *(bf16x8*)(sB + br * 64 + ((g ^ (br & 7)) << 3));
            acc[0][nt] = __builtin_amdgcn_mfma_f32_16x16x32_bf16(a0, b, acc[0][nt], 0, 0, 0);
            acc[1][nt] = __builtin_amdgcn_mfma_f32_16x16x32_bf16(a1, b, acc[1][nt], 0, 0, 0);
        }
    }
#pragma unroll
    for (int nt = 0; nt < 4; ++nt) {
        int col = j0 + nt * 16 + (lane & 15);
        float bias = dtb[col];
#pragma unroll
        for (int m = 0; m < 2; ++m)
#pragma unroll
            for (int j = 0; j < 4; ++j) {
                int row = i0 + R + m * 16 + ((lane >> 4) << 2) + j;
                delta[(size_t)row * Dm + col] = softplus_f(acc[m][nt][j] + bias);
            }
    }
}

// ---- helper: load A row, pre-scaled by log2(e), into regs ----
__device__ inline void load_a2(const float* __restrict__ A_log, int d, float* a2) {
    const float4* Ap = (const float4*)(A_log + (size_t)d * Ns);
    float4 a0 = Ap[0], a1 = Ap[1], a2v = Ap[2], a3 = Ap[3];
    float tmp[Ns] = {a0.x,a0.y,a0.z,a0.w, a1.x,a1.y,a1.z,a1.w,
                     a2v.x,a2v.y,a2v.z,a2v.w, a3.x,a3.y,a3.z,a3.w};
#pragma unroll
    for (int n = 0; n < Ns; ++n) a2[n] = -__expf(tmp[n]) * LOG2E;
}

// ========== Kernel 4: per-chunk local scan (h0=0) -> Ec, Sc  (R9 verbatim) ==========
template<int CHv>
__global__ void __launch_bounds__(NTHR)
k_scan_part(const float* __restrict__ delta, const float* __restrict__ x,
            const float* __restrict__ xp, const float* __restrict__ A_log,
            float* __restrict__ Ec, float* __restrict__ Sc) {
    constexpr int CLv = Ll / CHv;
    int bx = blockIdx.x;
    int dblk = bx & 3, chunk = (bx >> 2) & (CHv - 1), b = bx >> 2 >> __builtin_ctz(CHv);
    int tid = threadIdx.x;
    int d = dblk * 256 + tid;
    int row0 = b * Ll + chunk * CLv;

    float a2[Ns], h[Ns];
    load_a2(A_log, d, a2);
#pragma unroll
    for (int n = 0; n < Ns; ++n) h[n] = 0.f;
    float sd = 0.f;

#pragma unroll 4
    for (int t = 0; t < CLv; ++t) {
        size_t row = (size_t)(row0 + t);
        float dl = delta[row * Dm + d];
        float xv = x[row * Dm + d];
        const float* bp = xp + row * Ee + Rr;
        float4 B0 = *(const float4*)(bp + 0),  B1 = *(const float4*)(bp + 4);
        float4 B2 = *(const float4*)(bp + 8),  B3 = *(const float4*)(bp + 12);
        float Bv[Ns] = {B0.x,B0.y,B0.z,B0.w, B1.x,B1.y,B1.z,B1.w,
                        B2.x,B2.y,B2.z,B2.w, B3.x,B3.y,B3.z,B3.w};
        float dx = dl * xv;
        sd += dl;
#pragma unroll
        for (int n = 0; n < Ns; ++n)
            h[n] = fmaf(ex2(dl * a2[n]), h[n], dx * Bv[n]);
    }
    size_t base = ((size_t)b * CHv + chunk) * Dm + d;
    float4* Ep = (float4*)(Ec + base * Ns);
    Ep[0] = make_float4(h[0],  h[1],  h[2],  h[3]);
    Ep[1] = make_float4(h[4],  h[5],  h[6],  h[7]);
    Ep[2] = make_float4(h[8],  h[9],  h[10], h[11]);
    Ep[3] = make_float4(h[12], h[13], h[14], h[15]);
    Sc[base] = sd;
}

// ========== Kernel 5a: within-group combine (R9 verbatim) ==========
template<int CHv, int G>
__global__ void __launch_bounds__(NTHR)
k_comb1(const float* __restrict__ Ec, const float* __restrict__ Sc,
        const float* __restrict__ A_log, float* __restrict__ Hloc,
        float* __restrict__ Spre, float* __restrict__ Eg, float* __restrict__ Sg) {
    constexpr int CPG = CHv / G;
    int gid = blockIdx.x * NTHR + threadIdx.x;   // Bb*G*Dm*Ns = 262144
    int n = gid & (Ns - 1);
    int d = (gid >> 4) & (Dm - 1);
    int g = (gid >> 14) & (G - 1);
    int b = gid >> 17;
    float a2 = -__expf(A_log[d * Ns + n]) * LOG2E;
    float h = 0.f, S = 0.f;
#pragma unroll
    for (int j = 0; j < CPG; ++j) {
        size_t base = ((size_t)b * CHv + g * CPG + j) * Dm + d;
        float e  = Ec[base * Ns + n];
        float sc = Sc[base];
        Hloc[base * Ns + n] = h;
        if (n == 0) Spre[base] = S;
        h = fmaf(ex2(a2 * sc), h, e);
        S += sc;
    }
    size_t gb = ((size_t)b * G + g) * Dm + d;
    Eg[gb * Ns + n] = h;
    if (n == 0) Sg[gb] = S;
}

// ========== Kernel 5b: across-group combine (R9 verbatim) ==========
template<int G>
__global__ void __launch_bounds__(NTHR)
k_comb2(const float* __restrict__ Eg, const float* __restrict__ Sg,
        const float* __restrict__ A_log, float* __restrict__ Hg) {
    int gid = blockIdx.x * NTHR + threadIdx.x;   // Bb*Dm*Ns = 32768
    int n = gid & (Ns - 1);
    int d = (gid >> 4) & (Dm - 1);
    int b = gid >> 14;
    float a2 = -__expf(A_log[d * Ns + n]) * LOG2E;
    float h = 0.f;
#pragma unroll
    for (int g = 0; g < G; ++g) {
        size_t gb = ((size_t)b * G + g) * Dm + d;
        Hg[gb * Ns + n] = h;
        h = fmaf(ex2(a2 * Sg[gb]), h, Eg[gb * Ns + n]);
    }
}

// ========== Kernel 6: full scan; h_in = Hloc + exp2(a2*Spre)*Hg  (R9 verbatim) ==========
template<int CHv, int G>
__global__ void __launch_bounds__(NTHR)
k_scan_full(const float* __restrict__ delta, const float* __restrict__ x,
            const float* __restrict__ xp, const float* __restrict__ A_log,
            const float* __restrict__ Dp, const float* __restrict__ Hloc,
            const float* __restrict__ Spre, const float* __restrict__ Hg,
            float* __restrict__ out) {
    constexpr int CLv = Ll / CHv;
    constexpr int CPG = CHv / G;
    int bx = blockIdx.x;
    int dblk = bx & 3, chunk = (bx >> 2) & (CHv - 1), b = bx >> 2 >> __builtin_ctz(CHv);
    int tid = threadIdx.x;
    int d = dblk * 256 + tid;
    int row0 = b * Ll + chunk * CLv;

    float a2[Ns], h[Ns];
    load_a2(A_log, d, a2);
    size_t base = ((size_t)b * CHv + chunk) * Dm + d;
    size_t gb   = ((size_t)b * G + chunk / CPG) * Dm + d;
    {
        float sp = Spre[base];
        const float4* Hl = (const float4*)(Hloc + base * Ns);
        const float4* Hp = (const float4*)(Hg + gb * Ns);
        float4 l0 = Hl[0], l1 = Hl[1], l2 = Hl[2], l3 = Hl[3];
        float4 g0 = Hp[0], g1 = Hp[1], g2 = Hp[2], g3 = Hp[3];
        float lv[Ns] = {l0.x,l0.y,l0.z,l0.w, l1.x,l1.y,l1.z,l1.w,
                        l2.x,l2.y,l2.z,l2.w, l3.x,l3.y,l3.z,l3.w};
        float gv[Ns] = {g0.x,g0.y,g0.z,g0.w, g1.x,g1.y,g1.z,g1.w,
                        g2.x,g2.y,g2.z,g2.w, g3.x,g3.y,g3.z,g3.w};
#pragma unroll
        for (int n = 0; n < Ns; ++n) h[n] = fmaf(ex2(a2[n] * sp), gv[n], lv[n]);
    }
    float Dval = Dp[d];

#pragma unroll 4
    for (int t = 0; t < CLv; ++t) {
        size_t row = (size_t)(row0 + t);
        float dl = delta[row * Dm + d];
        float xv = x[row * Dm + d];
        const float* bp = xp + row * Ee + Rr;
        float4 B0 = *(const float4*)(bp + 0),  B1 = *(const float4*)(bp + 4);
        float4 B2 = *(const float4*)(bp + 8),  B3 = *(const float4*)(bp + 12);
        float4 C0 = *(const float4*)(bp + 16), C1 = *(const float4*)(bp + 20);
        float4 C2 = *(const float4*)(bp + 24), C3 = *(const float4*)(bp + 28);
        float Bv[Ns] = {B0.x,B0.y,B0.z,B0.w, B1.x,B1.y,B1.z,B1.w,
                        B2.x,B2.y,B2.z,B2.w, B3.x,B3.y,B3.z,B3.w};
        float Cv[Ns] = {C0.x,C0.y,C0.z,C0.w, C1.x,C1.y,C1.z,C1.w,
                        C2.x,C2.y,C2.z,C2.w, C3.x,C3.y,C3.z,C3.w};
        float dx = dl * xv;
        float ya[4] = {0.f, 0.f, 0.f, 0.f};
#pragma unroll
        for (int n = 0; n < Ns; ++n) {
            h[n] = fmaf(ex2(dl * a2[n]), h[n], dx * Bv[n]);
            ya[n & 3] = fmaf(h[n], Cv[n], ya[n & 3]);
        }
        out[row * Dm + d] = fmaf(xv, Dval, (ya[0] + ya[1]) + (ya[2] + ya[3]));
    }
}

extern "C" void kernel_launch(void* const* d_in, const int* in_sizes, int n_in,
                              void* d_out, int out_size, void* d_ws, size_t ws_size,
                              hipStream_t stream) {
    const float* x     = (const float*)d_in[0];
    const float* A_log = (const float*)d_in[1];
    const float* Dp    = (const float*)d_in[2];
    const float* xw    = (const float*)d_in[3];
    const float* dtw   = (const float*)d_in[4];
    const float* dtb   = (const float*)d_in[5];
    float* out = (float*)d_out;
    float* ws  = (float*)d_ws;

    // layout (floats):
    //   xp    : 393216
    //   delta : 4194304
    //   S3    : phase 1: xp_part = 8*393216 = 3145728  [dead after k_prep]
    //           phase 3+: Ec | Sc | Hloc | Spre | Eg | Sg | Hg  (CH=128: ~9.45M)
    float* xp      = ws;
    float* delta   = xp + 393216;
    float* S3      = delta + 4194304;
    float* xp_part = S3;

    k_xproj<<<dim3(2048), dim3(NTHR), 0, stream>>>(x, xw, xp_part);
    k_prep <<<dim3(384),  dim3(NTHR), 0, stream>>>(xp_part, xp);
    k_delta<<<dim3(512),  dim3(NTHR), 0, stream>>>(xp, dtw, dtb, delta);

    constexpr int G = 8;
    constexpr int CHv = 128;                    // ONLY change vs R9: 64 -> 128
    float* Ec   = S3;
    float* Sc   = Ec   + (size_t)Bb*CHv*Dm*Ns;
    float* Hloc = Sc   + (size_t)Bb*CHv*Dm;
    float* Spre = Hloc + (size_t)Bb*CHv*Dm*Ns;
    float* Eg   = Spre + (size_t)Bb*CHv*Dm;
    float* Sg   = Eg   + (size_t)Bb*G*Dm*Ns;
    float* Hg   = Sg   + (size_t)Bb*G*Dm;

    k_scan_part<CHv>  <<<dim3(Bb*CHv*4), dim3(NTHR), 0, stream>>>(delta, x, xp, A_log, Ec, Sc);
    k_comb1<CHv, G>   <<<dim3(Bb*G*Dm*Ns/NTHR), dim3(NTHR), 0, stream>>>(Ec, Sc, A_log, Hloc, Spre, Eg, Sg);
    k_comb2<G>        <<<dim3(Bb*Dm*Ns/NTHR), dim3(NTHR), 0, stream>>>(Eg, Sg, A_log, Hg);
    k_scan_full<CHv,G><<<dim3(Bb*CHv*4), dim3(NTHR), 0, stream>>>(delta, x, xp, A_log, Dp, Hloc, Spre, Hg, out);
}

// Round 13
// 136.278 us; speedup vs baseline: 1.0827x; 1.0079x over previous
//
#include <hip/hip_runtime.h>
#include <math.h>

#define Bb 2
#define Ll 2048
#define Dm 1024
#define Ns 16
#define Rr 64
#define Ee 96          // DT_RANK + 2*D_STATE
#define XPS 8          // K-splits for xproj GEMM (K-slice = 128)
#define BLK (Bb*Ll)    // 4096 rows
#define NTHR 256
#define LOG2E 1.4426950408889634f
#define LN2   0.6931471805599453f

typedef __attribute__((ext_vector_type(8))) short bf16x8;
typedef __attribute__((ext_vector_type(4))) float f32x4;

__device__ inline float ex2(float x) {
#if __has_builtin(__builtin_amdgcn_exp2f)
    return __builtin_amdgcn_exp2f(x);
#else
    return exp2f(x);
#endif
}
__device__ inline float lg2(float x) {
#if __has_builtin(__builtin_amdgcn_logf)
    return __builtin_amdgcn_logf(x);
#else
    return log2f(x);
#endif
}
__device__ inline float softplus_f(float z) {
    float e = ex2(-fabsf(z) * LOG2E);
    return fmaxf(z, 0.f) + lg2(1.f + e) * LN2;
}

// f32 -> bf16 with round-to-nearest-even
__device__ inline unsigned short f2bf(float f) {
    union { float f; unsigned u; } v; v.f = f;
    unsigned u = v.u + 0x7fffu + ((v.u >> 16) & 1u);
    return (unsigned short)(u >> 16);
}
__device__ inline uint2 pack4(float a, float b, float c, float d) {
    unsigned u0 = ((unsigned)f2bf(b) << 16) | f2bf(a);
    unsigned u1 = ((unsigned)f2bf(d) << 16) | f2bf(c);
    return make_uint2(u0, u1);
}

// ========== Kernel 1: xp_part[ks][bl][e]  (bf16 MFMA; R9 verbatim) ==========
__global__ void __launch_bounds__(NTHR, 4)
k_xproj(const float* __restrict__ x, const float* __restrict__ xw,
        float* __restrict__ xp_part) {
    __shared__ __align__(16) short sm[16*128 + 96*128];   // A | B ; f32 reduce alias
    int tid = threadIdx.x, lane = tid & 63, wid = tid >> 6;
    int bx = blockIdx.x;
    int ks = bx & 7, mt = bx >> 3;
    int i0 = mt * 16;
    int kb = ks * 128;
    short* sA = sm;
    short* sB = sm + 16*128;

#pragma unroll
    for (int i = 0; i < 2; ++i) {
        int idx = tid + i * 256;
        int r = idx >> 5, c4 = idx & 31;
        float4 v = *(const float4*)(x + (size_t)(i0 + r) * Dm + kb + c4 * 4);
        int unit = (c4 >> 1) ^ (r & 7);
        *(uint2*)(sA + r * 128 + unit * 8 + (c4 & 1) * 4) = pack4(v.x, v.y, v.z, v.w);
    }
#pragma unroll
    for (int i = 0; i < 12; ++i) {
        int idx = tid + i * 256;
        int r = idx >> 5, c4 = idx & 31;
        float4 v = *(const float4*)(xw + (size_t)r * Dm + kb + c4 * 4);
        int unit = (c4 >> 1) ^ (r & 7);
        *(uint2*)(sB + r * 128 + unit * 8 + (c4 & 1) * 4) = pack4(v.x, v.y, v.z, v.w);
    }
    __syncthreads();

    f32x4 acc[6];
#pragma unroll
    for (int t = 0; t < 6; ++t) acc[t] = (f32x4)0.f;
    int ra = lane & 15;
    int g = wid * 4 + (lane >> 4);                 // 0..15
    bf16x8 a = *(bf16x8*)(sA + ra * 128 + ((g ^ (ra & 7)) << 3));
#pragma unroll
    for (int nt = 0; nt < 6; ++nt) {
        int br = nt * 16 + (lane & 15);
        bf16x8 b = *(bf16x8*)(sB + br * 128 + ((g ^ (br & 7)) << 3));
        acc[nt] = __builtin_amdgcn_mfma_f32_16x16x32_bf16(a, b, acc[nt], 0, 0, 0);
    }
    __syncthreads();

    float* rp = (float*)sm;
#pragma unroll
    for (int nt = 0; nt < 6; ++nt)
#pragma unroll
        for (int j = 0; j < 4; ++j) {
            int r = ((lane >> 4) << 2) + j;
            int c = nt * 16 + (lane & 15);
            rp[wid * 1536 + r * 96 + c] = acc[nt][j];
        }
    __syncthreads();
#pragma unroll
    for (int o = 0; o < 6; ++o) {
        int idx = o * 256 + tid;
        float s = rp[idx] + rp[1536 + idx] + rp[3072 + idx] + rp[4608 + idx];
        int r = idx / 96, c = idx - r * 96;
        xp_part[((size_t)ks * BLK + (i0 + r)) * Ee + c] = s;
    }
}

// ========== Kernel 2: reduce K-splits -> xp (verbatim) ==========
__global__ void __launch_bounds__(NTHR)
k_prep(const float* __restrict__ xp_part, float* __restrict__ xp) {
    int g = blockIdx.x * NTHR + threadIdx.x;    // 98304 float4s
    const float4* p = (const float4*)xp_part;
    float4 s = p[g];
#pragma unroll
    for (int i = 1; i < XPS; ++i) {
        float4 v = p[(size_t)i * (BLK * Ee / 4) + g];
        s.x += v.x; s.y += v.y; s.z += v.z; s.w += v.w;
    }
    ((float4*)xp)[g] = s;
}

// ========== Kernel 3: delta = softplus(xp[:, :64] . dtw^T + dtb)  (bf16 MFMA) ==========
// BM=64, BN=64 -> grid 1024 (4 blocks/CU, was 2). 4 waves, each 16x64 (8 MFMA).
// MFMA accumulation order per element unchanged vs BM=128 -> delta bit-identical.
__global__ void __launch_bounds__(NTHR)
k_delta(const float* __restrict__ xp, const float* __restrict__ dtw,
        const float* __restrict__ dtb, float* __restrict__ delta) {
    __shared__ __align__(16) short sA[64 * 64];
    __shared__ __align__(16) short sB[64 * 64];
    int tid = threadIdx.x, lane = tid & 63, wid = tid >> 6;
    int nt16 = blockIdx.x & 15, mt = blockIdx.x >> 4;
    int i0 = mt * 64, j0 = nt16 * 64;

#pragma unroll
    for (int i = 0; i < 4; ++i) {               // A: 64x64 from xp (f32 -> bf16)
        int idx = tid + i * 256;
        int r = idx >> 4, c4 = idx & 15;
        float4 v = *(const float4*)(xp + (size_t)(i0 + r) * Ee + c4 * 4);
        int unit = (c4 >> 1) ^ (r & 7);
        *(uint2*)(sA + r * 64 + unit * 8 + (c4 & 1) * 4) = pack4(v.x, v.y, v.z, v.w);
    }
#pragma unroll
    for (int i = 0; i < 4; ++i) {               // B: 64x64 from dtw
        int idx = tid + i * 256;
        int r = idx >> 4, c4 = idx & 15;
        float4 v = *(const float4*)(dtw + (size_t)(j0 + r) * Rr + c4 * 4);
        int unit = (c4 >> 1) ^ (r & 7);
        *(uint2*)(sB + r * 64 + unit * 8 + (c4 & 1) * 4) = pack4(v.x, v.y, v.z, v.w);
    }
    __syncthreads();

    f32x4 acc[4];
#pragma unroll
    for (int nt = 0; nt < 4; ++nt) acc[nt] = (f32x4)0.f;
    int R = wid * 16;
    int r0 = R + (lane & 15);
#pragma unroll
    for (int ks = 0; ks < 2; ++ks) {
        int g = ks * 4 + (lane >> 4);
        bf16x8 a0 = *(bf16x8*)(sA + r0 * 64 + ((g ^ (r0 & 7)) << 3));
#pragma unroll
        for (int nt = 0; nt < 4; ++nt) {
            int br = nt * 16 + (lane & 15);
            bf16x8 b = *(bf16x8*)(sB + br * 64 + ((g ^ (br & 7)) << 3));
            acc[nt] = __builtin_amdgcn_mfma_f32_16x16x32_bf16(a0, b, acc[nt], 0, 0, 0);
        }
    }
#pragma unroll
    for (int nt = 0; nt < 4; ++nt) {
        int col = j0 + nt * 16 + (lane & 15);
        float bias = dtb[col];
#pragma unroll
        for (int j = 0; j < 4; ++j) {
            int row = i0 + R + ((lane >> 4) << 2) + j;
            delta[(size_t)row * Dm + col] = softplus_f(acc[nt][j] + bias);
        }
    }
}

// ---- helper: load A row, pre-scaled by log2(e), into regs ----
__device__ inline void load_a2(const float* __restrict__ A_log, int d, float* a2) {
    const float4* Ap = (const float4*)(A_log + (size_t)d * Ns);
    float4 a0 = Ap[0], a1 = Ap[1], a2v = Ap[2], a3 = Ap[3];
    float tmp[Ns] = {a0.x,a0.y,a0.z,a0.w, a1.x,a1.y,a1.z,a1.w,
                     a2v.x,a2v.y,a2v.z,a2v.w, a3.x,a3.y,a3.z,a3.w};
#pragma unroll
    for (int n = 0; n < Ns; ++n) a2[n] = -__expf(tmp[n]) * LOG2E;
}

// ========== Kernel 4: per-chunk local scan (h0=0) -> Ec, Sc  (R9 verbatim) ==========
template<int CHv>
__global__ void __launch_bounds__(NTHR)
k_scan_part(const float* __restrict__ delta, const float* __restrict__ x,
            const float* __restrict__ xp, const float* __restrict__ A_log,
            float* __restrict__ Ec, float* __restrict__ Sc) {
    constexpr int CLv = Ll / CHv;
    int bx = blockIdx.x;
    int dblk = bx & 3, chunk = (bx >> 2) & (CHv - 1), b = bx >> 2 >> __builtin_ctz(CHv);
    int tid = threadIdx.x;
    int d = dblk * 256 + tid;
    int row0 = b * Ll + chunk * CLv;

    float a2[Ns], h[Ns];
    load_a2(A_log, d, a2);
#pragma unroll
    for (int n = 0; n < Ns; ++n) h[n] = 0.f;
    float sd = 0.f;

#pragma unroll 4
    for (int t = 0; t < CLv; ++t) {
        size_t row = (size_t)(row0 + t);
        float dl = delta[row * Dm + d];
        float xv = x[row * Dm + d];
        const float* bp = xp + row * Ee + Rr;
        float4 B0 = *(const float4*)(bp + 0),  B1 = *(const float4*)(bp + 4);
        float4 B2 = *(const float4*)(bp + 8),  B3 = *(const float4*)(bp + 12);
        float Bv[Ns] = {B0.x,B0.y,B0.z,B0.w, B1.x,B1.y,B1.z,B1.w,
                        B2.x,B2.y,B2.z,B2.w, B3.x,B3.y,B3.z,B3.w};
        float dx = dl * xv;
        sd += dl;
#pragma unroll
        for (int n = 0; n < Ns; ++n)
            h[n] = fmaf(ex2(dl * a2[n]), h[n], dx * Bv[n]);
    }
    size_t base = ((size_t)b * CHv + chunk) * Dm + d;
    float4* Ep = (float4*)(Ec + base * Ns);
    Ep[0] = make_float4(h[0],  h[1],  h[2],  h[3]);
    Ep[1] = make_float4(h[4],  h[5],  h[6],  h[7]);
    Ep[2] = make_float4(h[8],  h[9],  h[10], h[11]);
    Ep[3] = make_float4(h[12], h[13], h[14], h[15]);
    Sc[base] = sd;
}

// ========== Kernel 5a: within-group combine (R9 verbatim) ==========
template<int CHv, int G>
__global__ void __launch_bounds__(NTHR)
k_comb1(const float* __restrict__ Ec, const float* __restrict__ Sc,
        const float* __restrict__ A_log, float* __restrict__ Hloc,
        float* __restrict__ Spre, float* __restrict__ Eg, float* __restrict__ Sg) {
    constexpr int CPG = CHv / G;
    int gid = blockIdx.x * NTHR + threadIdx.x;   // Bb*G*Dm*Ns = 262144
    int n = gid & (Ns - 1);
    int d = (gid >> 4) & (Dm - 1);
    int g = (gid >> 14) & (G - 1);
    int b = gid >> 17;
    float a2 = -__expf(A_log[d * Ns + n]) * LOG2E;
    float h = 0.f, S = 0.f;
#pragma unroll
    for (int j = 0; j < CPG; ++j) {
        size_t base = ((size_t)b * CHv + g * CPG + j) * Dm + d;
        float e  = Ec[base * Ns + n];
        float sc = Sc[base];
        Hloc[base * Ns + n] = h;
        if (n == 0) Spre[base] = S;
        h = fmaf(ex2(a2 * sc), h, e);
        S += sc;
    }
    size_t gb = ((size_t)b * G + g) * Dm + d;
    Eg[gb * Ns + n] = h;
    if (n == 0) Sg[gb] = S;
}

// ========== Kernel 5b: across-group combine (R9 verbatim) ==========
template<int G>
__global__ void __launch_bounds__(NTHR)
k_comb2(const float* __restrict__ Eg, const float* __restrict__ Sg,
        const float* __restrict__ A_log, float* __restrict__ Hg) {
    int gid = blockIdx.x * NTHR + threadIdx.x;   // Bb*Dm*Ns = 32768
    int n = gid & (Ns - 1);
    int d = (gid >> 4) & (Dm - 1);
    int b = gid >> 14;
    float a2 = -__expf(A_log[d * Ns + n]) * LOG2E;
    float h = 0.f;
#pragma unroll
    for (int g = 0; g < G; ++g) {
        size_t gb = ((size_t)b * G + g) * Dm + d;
        Hg[gb * Ns + n] = h;
        h = fmaf(ex2(a2 * Sg[gb]), h, Eg[gb * Ns + n]);
    }
}

// ========== Kernel 6: full scan; h_in = Hloc + exp2(a2*Spre)*Hg  (R9 verbatim) ==========
template<int CHv, int G>
__global__ void __launch_bounds__(NTHR)
k_scan_full(const float* __restrict__ delta, const float* __restrict__ x,
            const float* __restrict__ xp, const float* __restrict__ A_log,
            const float* __restrict__ Dp, const float* __restrict__ Hloc,
            const float* __restrict__ Spre, const float* __restrict__ Hg,
            float* __restrict__ out) {
    constexpr int CLv = Ll / CHv;
    constexpr int CPG = CHv / G;
    int bx = blockIdx.x;
    int dblk = bx & 3, chunk = (bx >> 2) & (CHv - 1), b = bx >> 2 >> __builtin_ctz(CHv);
    int tid = threadIdx.x;
    int d = dblk * 256 + tid;
    int row0 = b * Ll + chunk * CLv;

    float a2[Ns], h[Ns];
    load_a2(A_log, d, a2);
    size_t base = ((size_t)b * CHv + chunk) * Dm + d;
    size_t gb   = ((size_t)b * G + chunk / CPG) * Dm + d;
    {
        float sp = Spre[base];
        const float4* Hl = (const float4*)(Hloc + base * Ns);
        const float4* Hp = (const float4*)(Hg + gb * Ns);
        float4 l0 = Hl[0], l1 = Hl[1], l2 = Hl[2], l3 = Hl[3];
        float4 g0 = Hp[0], g1 = Hp[1], g2 = Hp[2], g3 = Hp[3];
        float lv[Ns] = {l0.x,l0.y,l0.z,l0.w, l1.x,l1.y,l1.z,l1.w,
                        l2.x,l2.y,l2.z,l2.w, l3.x,l3.y,l3.z,l3.w};
        float gv[Ns] = {g0.x,g0.y,g0.z,g0.w, g1.x,g1.y,g1.z,g1.w,
                        g2.x,g2.y,g2.z,g2.w, g3.x,g3.y,g3.z,g3.w};
#pragma unroll
        for (int n = 0; n < Ns; ++n) h[n] = fmaf(ex2(a2[n] * sp), gv[n], lv[n]);
    }
    float Dval = Dp[d];

#pragma unroll 4
    for (int t = 0; t < CLv; ++t) {
        size_t row = (size_t)(row0 + t);
        float dl = delta[row * Dm + d];
        float xv = x[row * Dm + d];
        const float* bp = xp + row * Ee + Rr;
        float4 B0 = *(const float4*)(bp + 0),  B1 = *(const float4*)(bp + 4);
        float4 B2 = *(const float4*)(bp + 8),  B3 = *(const float4*)(bp + 12);
        float4 C0 = *(const float4*)(bp + 16), C1 = *(const float4*)(bp + 20);
        float4 C2 = *(const float4*)(bp + 24), C3 = *(const float4*)(bp + 28);
        float Bv[Ns] = {B0.x,B0.y,B0.z,B0.w, B1.x,B1.y,B1.z,B1.w,
                        B2.x,B2.y,B2.z,B2.w, B3.x,B3.y,B3.z,B3.w};
        float Cv[Ns] = {C0.x,C0.y,C0.z,C0.w, C1.x,C1.y,C1.z,C1.w,
                        C2.x,C2.y,C2.z,C2.w, C3.x,C3.y,C3.z,C3.w};
        float dx = dl * xv;
        float ya[4] = {0.f, 0.f, 0.f, 0.f};
#pragma unroll
        for (int n = 0; n < Ns; ++n) {
            h[n] = fmaf(ex2(dl * a2[n]), h[n], dx * Bv[n]);
            ya[n & 3] = fmaf(h[n], Cv[n], ya[n & 3]);
        }
        out[row * Dm + d] = fmaf(xv, Dval, (ya[0] + ya[1]) + (ya[2] + ya[3]));
    }
}

extern "C" void kernel_launch(void* const* d_in, const int* in_sizes, int n_in,
                              void* d_out, int out_size, void* d_ws, size_t ws_size,
                              hipStream_t stream) {
    const float* x     = (const float*)d_in[0];
    const float* A_log = (const float*)d_in[1];
    const float* Dp    = (const float*)d_in[2];
    const float* xw    = (const float*)d_in[3];
    const float* dtw   = (const float*)d_in[4];
    const float* dtb   = (const float*)d_in[5];
    float* out = (float*)d_out;
    float* ws  = (float*)d_ws;

    // layout (floats):
    //   xp    : 393216
    //   delta : 4194304
    //   S3    : phase 1: xp_part = 8*393216 = 3145728  [dead after k_prep]
    //           phase 3+: Ec | Sc | Hloc | Spre | Eg | Sg | Hg  (CH=64: ~5.0M)
    float* xp      = ws;
    float* delta   = xp + 393216;
    float* S3      = delta + 4194304;
    float* xp_part = S3;

    k_xproj<<<dim3(2048), dim3(NTHR), 0, stream>>>(x, xw, xp_part);
    k_prep <<<dim3(384),  dim3(NTHR), 0, stream>>>(xp_part, xp);
    k_delta<<<dim3(1024), dim3(NTHR), 0, stream>>>(xp, dtw, dtb, delta);

    constexpr int G = 8;
    constexpr int CHv = 64;                     // revert to R9 (R12: CH=128 null)
    float* Ec   = S3;
    float* Sc   = Ec   + (size_t)Bb*CHv*Dm*Ns;
    float* Hloc = Sc   + (size_t)Bb*CHv*Dm;
    float* Spre = Hloc + (size_t)Bb*CHv*Dm*Ns;
    float* Eg   = Spre + (size_t)Bb*CHv*Dm;
    float* Sg   = Eg   + (size_t)Bb*G*Dm*Ns;
    float* Hg   = Sg   + (size_t)Bb*G*Dm;

    k_scan_part<CHv>  <<<dim3(Bb*CHv*4), dim3(NTHR), 0, stream>>>(delta, x, xp, A_log, Ec, Sc);
    k_comb1<CHv, G>   <<<dim3(Bb*G*Dm*Ns/NTHR), dim3(NTHR), 0, stream>>>(Ec, Sc, A_log, Hloc, Spre, Eg, Sg);
    k_comb2<G>        <<<dim3(Bb*Dm*Ns/NTHR), dim3(NTHR), 0, stream>>>(Eg, Sg, A_log, Hg);
    k_scan_full<CHv,G><<<dim3(Bb*CHv*4), dim3(NTHR), 0, stream>>>(delta, x, xp, A_log, Dp, Hloc, Spre, Hg, out);
}

// Round 14
// 134.682 us; speedup vs baseline: 1.0955x; 1.0119x over previous
//
#include <hip/hip_runtime.h>
#include <math.h>

#define Bb 2
#define Ll 2048
#define Dm 1024
#define Ns 16
#define Rr 64
#define Ee 96          // DT_RANK + 2*D_STATE
#define XPS 8          // K-splits for xproj GEMM (K-slice = 128)
#define BLK (Bb*Ll)    // 4096 rows
#define NTHR 256
#define LOG2E 1.4426950408889634f
#define LN2   0.6931471805599453f

typedef __attribute__((ext_vector_type(8))) short bf16x8;
typedef __attribute__((ext_vector_type(4))) float f32x4;

__device__ inline float ex2(float x) {
#if __has_builtin(__builtin_amdgcn_exp2f)
    return __builtin_amdgcn_exp2f(x);
#else
    return exp2f(x);
#endif
}
__device__ inline float lg2(float x) {
#if __has_builtin(__builtin_amdgcn_logf)
    return __builtin_amdgcn_logf(x);
#else
    return log2f(x);
#endif
}
__device__ inline float softplus_f(float z) {
    float e = ex2(-fabsf(z) * LOG2E);
    return fmaxf(z, 0.f) + lg2(1.f + e) * LN2;
}

// f32 -> bf16 with round-to-nearest-even
__device__ inline unsigned short f2bf(float f) {
    union { float f; unsigned u; } v; v.f = f;
    unsigned u = v.u + 0x7fffu + ((v.u >> 16) & 1u);
    return (unsigned short)(u >> 16);
}
__device__ inline float bf2f(unsigned short u) {
    union { unsigned u; float f; } v; v.u = (unsigned)u << 16;
    return v.f;
}
__device__ inline uint2 pack4(float a, float b, float c, float d) {
    unsigned u0 = ((unsigned)f2bf(b) << 16) | f2bf(a);
    unsigned u1 = ((unsigned)f2bf(d) << 16) | f2bf(c);
    return make_uint2(u0, u1);
}

// ========== Kernel 1: xp_part[ks][bl][e]  (bf16 MFMA; R9 verbatim) ==========
__global__ void __launch_bounds__(NTHR, 4)
k_xproj(const float* __restrict__ x, const float* __restrict__ xw,
        float* __restrict__ xp_part) {
    __shared__ __align__(16) short sm[16*128 + 96*128];   // A | B ; f32 reduce alias
    int tid = threadIdx.x, lane = tid & 63, wid = tid >> 6;
    int bx = blockIdx.x;
    int ks = bx & 7, mt = bx >> 3;
    int i0 = mt * 16;
    int kb = ks * 128;
    short* sA = sm;
    short* sB = sm + 16*128;

#pragma unroll
    for (int i = 0; i < 2; ++i) {
        int idx = tid + i * 256;
        int r = idx >> 5, c4 = idx & 31;
        float4 v = *(const float4*)(x + (size_t)(i0 + r) * Dm + kb + c4 * 4);
        int unit = (c4 >> 1) ^ (r & 7);
        *(uint2*)(sA + r * 128 + unit * 8 + (c4 & 1) * 4) = pack4(v.x, v.y, v.z, v.w);
    }
#pragma unroll
    for (int i = 0; i < 12; ++i) {
        int idx = tid + i * 256;
        int r = idx >> 5, c4 = idx & 31;
        float4 v = *(const float4*)(xw + (size_t)r * Dm + kb + c4 * 4);
        int unit = (c4 >> 1) ^ (r & 7);
        *(uint2*)(sB + r * 128 + unit * 8 + (c4 & 1) * 4) = pack4(v.x, v.y, v.z, v.w);
    }
    __syncthreads();

    f32x4 acc[6];
#pragma unroll
    for (int t = 0; t < 6; ++t) acc[t] = (f32x4)0.f;
    int ra = lane & 15;
    int g = wid * 4 + (lane >> 4);                 // 0..15
    bf16x8 a = *(bf16x8*)(sA + ra * 128 + ((g ^ (ra & 7)) << 3));
#pragma unroll
    for (int nt = 0; nt < 6; ++nt) {
        int br = nt * 16 + (lane & 15);
        bf16x8 b = *(bf16x8*)(sB + br * 128 + ((g ^ (br & 7)) << 3));
        acc[nt] = __builtin_amdgcn_mfma_f32_16x16x32_bf16(a, b, acc[nt], 0, 0, 0);
    }
    __syncthreads();

    float* rp = (float*)sm;
#pragma unroll
    for (int nt = 0; nt < 6; ++nt)
#pragma unroll
        for (int j = 0; j < 4; ++j) {
            int r = ((lane >> 4) << 2) + j;
            int c = nt * 16 + (lane & 15);
            rp[wid * 1536 + r * 96 + c] = acc[nt][j];
        }
    __syncthreads();
#pragma unroll
    for (int o = 0; o < 6; ++o) {
        int idx = o * 256 + tid;
        float s = rp[idx] + rp[1536 + idx] + rp[3072 + idx] + rp[4608 + idx];
        int r = idx / 96, c = idx - r * 96;
        xp_part[((size_t)ks * BLK + (i0 + r)) * Ee + c] = s;
    }
}

// ========== Kernel 2: reduce K-splits -> xp (verbatim) ==========
__global__ void __launch_bounds__(NTHR)
k_prep(const float* __restrict__ xp_part, float* __restrict__ xp) {
    int g = blockIdx.x * NTHR + threadIdx.x;    // 98304 float4s
    const float4* p = (const float4*)xp_part;
    float4 s = p[g];
#pragma unroll
    for (int i = 1; i < XPS; ++i) {
        float4 v = p[(size_t)i * (BLK * Ee / 4) + g];
        s.x += v.x; s.y += v.y; s.z += v.z; s.w += v.w;
    }
    ((float4*)xp)[g] = s;
}

// ========== Kernel 3: delta = softplus(xp[:, :64] . dtw^T + dtb)  (bf16 MFMA; R13 verbatim) ==========
__global__ void __launch_bounds__(NTHR)
k_delta(const float* __restrict__ xp, const float* __restrict__ dtw,
        const float* __restrict__ dtb, float* __restrict__ delta) {
    __shared__ __align__(16) short sA[64 * 64];
    __shared__ __align__(16) short sB[64 * 64];
    int tid = threadIdx.x, lane = tid & 63, wid = tid >> 6;
    int nt16 = blockIdx.x & 15, mt = blockIdx.x >> 4;
    int i0 = mt * 64, j0 = nt16 * 64;

#pragma unroll
    for (int i = 0; i < 4; ++i) {               // A: 64x64 from xp (f32 -> bf16)
        int idx = tid + i * 256;
        int r = idx >> 4, c4 = idx & 15;
        float4 v = *(const float4*)(xp + (size_t)(i0 + r) * Ee + c4 * 4);
        int unit = (c4 >> 1) ^ (r & 7);
        *(uint2*)(sA + r * 64 + unit * 8 + (c4 & 1) * 4) = pack4(v.x, v.y, v.z, v.w);
    }
#pragma unroll
    for (int i = 0; i < 4; ++i) {               // B: 64x64 from dtw
        int idx = tid + i * 256;
        int r = idx >> 4, c4 = idx & 15;
        float4 v = *(const float4*)(dtw + (size_t)(j0 + r) * Rr + c4 * 4);
        int unit = (c4 >> 1) ^ (r & 7);
        *(uint2*)(sB + r * 64 + unit * 8 + (c4 & 1) * 4) = pack4(v.x, v.y, v.z, v.w);
    }
    __syncthreads();

    f32x4 acc[4];
#pragma unroll
    for (int nt = 0; nt < 4; ++nt) acc[nt] = (f32x4)0.f;
    int R = wid * 16;
    int r0 = R + (lane & 15);
#pragma unroll
    for (int ks = 0; ks < 2; ++ks) {
        int g = ks * 4 + (lane >> 4);
        bf16x8 a0 = *(bf16x8*)(sA + r0 * 64 + ((g ^ (r0 & 7)) << 3));
#pragma unroll
        for (int nt = 0; nt < 4; ++nt) {
            int br = nt * 16 + (lane & 15);
            bf16x8 b = *(bf16x8*)(sB + br * 64 + ((g ^ (br & 7)) << 3));
            acc[nt] = __builtin_amdgcn_mfma_f32_16x16x32_bf16(a0, b, acc[nt], 0, 0, 0);
        }
    }
#pragma unroll
    for (int nt = 0; nt < 4; ++nt) {
        int col = j0 + nt * 16 + (lane & 15);
        float bias = dtb[col];
#pragma unroll
        for (int j = 0; j < 4; ++j) {
            int row = i0 + R + ((lane >> 4) << 2) + j;
            delta[(size_t)row * Dm + col] = softplus_f(acc[nt][j] + bias);
        }
    }
}

// ---- helper: load A row, pre-scaled by log2(e), into regs ----
__device__ inline void load_a2(const float* __restrict__ A_log, int d, float* a2) {
    const float4* Ap = (const float4*)(A_log + (size_t)d * Ns);
    float4 a0 = Ap[0], a1 = Ap[1], a2v = Ap[2], a3 = Ap[3];
    float tmp[Ns] = {a0.x,a0.y,a0.z,a0.w, a1.x,a1.y,a1.z,a1.w,
                     a2v.x,a2v.y,a2v.z,a2v.w, a3.x,a3.y,a3.z,a3.w};
#pragma unroll
    for (int n = 0; n < Ns; ++n) a2[n] = -__expf(tmp[n]) * LOG2E;
}

// ========== Kernel 4: per-chunk local scan (h0=0) -> Ec(bf16), Sc(f32) ==========
template<int CHv>
__global__ void __launch_bounds__(NTHR)
k_scan_part(const float* __restrict__ delta, const float* __restrict__ x,
            const float* __restrict__ xp, const float* __restrict__ A_log,
            unsigned short* __restrict__ Ec, float* __restrict__ Sc) {
    constexpr int CLv = Ll / CHv;
    int bx = blockIdx.x;
    int dblk = bx & 3, chunk = (bx >> 2) & (CHv - 1), b = bx >> 2 >> __builtin_ctz(CHv);
    int tid = threadIdx.x;
    int d = dblk * 256 + tid;
    int row0 = b * Ll + chunk * CLv;

    float a2[Ns], h[Ns];
    load_a2(A_log, d, a2);
#pragma unroll
    for (int n = 0; n < Ns; ++n) h[n] = 0.f;
    float sd = 0.f;

#pragma unroll 4
    for (int t = 0; t < CLv; ++t) {
        size_t row = (size_t)(row0 + t);
        float dl = delta[row * Dm + d];
        float xv = x[row * Dm + d];
        const float* bp = xp + row * Ee + Rr;
        float4 B0 = *(const float4*)(bp + 0),  B1 = *(const float4*)(bp + 4);
        float4 B2 = *(const float4*)(bp + 8),  B3 = *(const float4*)(bp + 12);
        float Bv[Ns] = {B0.x,B0.y,B0.z,B0.w, B1.x,B1.y,B1.z,B1.w,
                        B2.x,B2.y,B2.z,B2.w, B3.x,B3.y,B3.z,B3.w};
        float dx = dl * xv;
        sd += dl;
#pragma unroll
        for (int n = 0; n < Ns; ++n)
            h[n] = fmaf(ex2(dl * a2[n]), h[n], dx * Bv[n]);
    }
    size_t base = ((size_t)b * CHv + chunk) * Dm + d;
    uint2 q0 = pack4(h[0],  h[1],  h[2],  h[3]);
    uint2 q1 = pack4(h[4],  h[5],  h[6],  h[7]);
    uint2 q2 = pack4(h[8],  h[9],  h[10], h[11]);
    uint2 q3 = pack4(h[12], h[13], h[14], h[15]);
    uint4* Ep = (uint4*)(Ec + base * Ns);
    Ep[0] = make_uint4(q0.x, q0.y, q1.x, q1.y);
    Ep[1] = make_uint4(q2.x, q2.y, q3.x, q3.y);
    Sc[base] = sd;
}

// ========== Kernel 5a: within-group combine (Ec/Hloc bf16) ==========
template<int CHv, int G>
__global__ void __launch_bounds__(NTHR)
k_comb1(const unsigned short* __restrict__ Ec, const float* __restrict__ Sc,
        const float* __restrict__ A_log, unsigned short* __restrict__ Hloc,
        float* __restrict__ Spre, float* __restrict__ Eg, float* __restrict__ Sg) {
    constexpr int CPG = CHv / G;
    int gid = blockIdx.x * NTHR + threadIdx.x;   // Bb*G*Dm*Ns = 262144
    int n = gid & (Ns - 1);
    int d = (gid >> 4) & (Dm - 1);
    int g = (gid >> 14) & (G - 1);
    int b = gid >> 17;
    float a2 = -__expf(A_log[d * Ns + n]) * LOG2E;
    float h = 0.f, S = 0.f;
#pragma unroll
    for (int j = 0; j < CPG; ++j) {
        size_t base = ((size_t)b * CHv + g * CPG + j) * Dm + d;
        float e  = bf2f(Ec[base * Ns + n]);
        float sc = Sc[base];
        Hloc[base * Ns + n] = f2bf(h);
        if (n == 0) Spre[base] = S;
        h = fmaf(ex2(a2 * sc), h, e);
        S += sc;
    }
    size_t gb = ((size_t)b * G + g) * Dm + d;
    Eg[gb * Ns + n] = h;
    if (n == 0) Sg[gb] = S;
}

// ========== Kernel 5b: across-group combine (f32; verbatim) ==========
template<int G>
__global__ void __launch_bounds__(NTHR)
k_comb2(const float* __restrict__ Eg, const float* __restrict__ Sg,
        const float* __restrict__ A_log, float* __restrict__ Hg) {
    int gid = blockIdx.x * NTHR + threadIdx.x;   // Bb*Dm*Ns = 32768
    int n = gid & (Ns - 1);
    int d = (gid >> 4) & (Dm - 1);
    int b = gid >> 14;
    float a2 = -__expf(A_log[d * Ns + n]) * LOG2E;
    float h = 0.f;
#pragma unroll
    for (int g = 0; g < G; ++g) {
        size_t gb = ((size_t)b * G + g) * Dm + d;
        Hg[gb * Ns + n] = h;
        h = fmaf(ex2(a2 * Sg[gb]), h, Eg[gb * Ns + n]);
    }
}

// ========== Kernel 6: full scan; h_in = Hloc(bf16) + exp2(a2*Spre)*Hg(f32) ==========
template<int CHv, int G>
__global__ void __launch_bounds__(NTHR)
k_scan_full(const float* __restrict__ delta, const float* __restrict__ x,
            const float* __restrict__ xp, const float* __restrict__ A_log,
            const float* __restrict__ Dp, const unsigned short* __restrict__ Hloc,
            const float* __restrict__ Spre, const float* __restrict__ Hg,
            float* __restrict__ out) {
    constexpr int CLv = Ll / CHv;
    constexpr int CPG = CHv / G;
    int bx = blockIdx.x;
    int dblk = bx & 3, chunk = (bx >> 2) & (CHv - 1), b = bx >> 2 >> __builtin_ctz(CHv);
    int tid = threadIdx.x;
    int d = dblk * 256 + tid;
    int row0 = b * Ll + chunk * CLv;

    float a2[Ns], h[Ns];
    load_a2(A_log, d, a2);
    size_t base = ((size_t)b * CHv + chunk) * Dm + d;
    size_t gb   = ((size_t)b * G + chunk / CPG) * Dm + d;
    {
        float sp = Spre[base];
        const uint4* Hl = (const uint4*)(Hloc + base * Ns);
        uint4 u0 = Hl[0], u1 = Hl[1];
        const float4* Hp = (const float4*)(Hg + gb * Ns);
        float4 g0 = Hp[0], g1 = Hp[1], g2 = Hp[2], g3 = Hp[3];
        unsigned w[8] = {u0.x,u0.y,u0.z,u0.w, u1.x,u1.y,u1.z,u1.w};
        float lv[Ns];
#pragma unroll
        for (int i = 0; i < 8; ++i) {
            lv[2*i]   = bf2f((unsigned short)(w[i] & 0xffffu));
            lv[2*i+1] = bf2f((unsigned short)(w[i] >> 16));
        }
        float gv[Ns] = {g0.x,g0.y,g0.z,g0.w, g1.x,g1.y,g1.z,g1.w,
                        g2.x,g2.y,g2.z,g2.w, g3.x,g3.y,g3.z,g3.w};
#pragma unroll
        for (int n = 0; n < Ns; ++n) h[n] = fmaf(ex2(a2[n] * sp), gv[n], lv[n]);
    }
    float Dval = Dp[d];

#pragma unroll 4
    for (int t = 0; t < CLv; ++t) {
        size_t row = (size_t)(row0 + t);
        float dl = delta[row * Dm + d];
        float xv = x[row * Dm + d];
        const float* bp = xp + row * Ee + Rr;
        float4 B0 = *(const float4*)(bp + 0),  B1 = *(const float4*)(bp + 4);
        float4 B2 = *(const float4*)(bp + 8),  B3 = *(const float4*)(bp + 12);
        float4 C0 = *(const float4*)(bp + 16), C1 = *(const float4*)(bp + 20);
        float4 C2 = *(const float4*)(bp + 24), C3 = *(const float4*)(bp + 28);
        float Bv[Ns] = {B0.x,B0.y,B0.z,B0.w, B1.x,B1.y,B1.z,B1.w,
                        B2.x,B2.y,B2.z,B2.w, B3.x,B3.y,B3.z,B3.w};
        float Cv[Ns] = {C0.x,C0.y,C0.z,C0.w, C1.x,C1.y,C1.z,C1.w,
                        C2.x,C2.y,C2.z,C2.w, C3.x,C3.y,C3.z,C3.w};
        float dx = dl * xv;
        float ya[4] = {0.f, 0.f, 0.f, 0.f};
#pragma unroll
        for (int n = 0; n < Ns; ++n) {
            h[n] = fmaf(ex2(dl * a2[n]), h[n], dx * Bv[n]);
            ya[n & 3] = fmaf(h[n], Cv[n], ya[n & 3]);
        }
        out[row * Dm + d] = fmaf(xv, Dval, (ya[0] + ya[1]) + (ya[2] + ya[3]));
    }
}

extern "C" void kernel_launch(void* const* d_in, const int* in_sizes, int n_in,
                              void* d_out, int out_size, void* d_ws, size_t ws_size,
                              hipStream_t stream) {
    const float* x     = (const float*)d_in[0];
    const float* A_log = (const float*)d_in[1];
    const float* Dp    = (const float*)d_in[2];
    const float* xw    = (const float*)d_in[3];
    const float* dtw   = (const float*)d_in[4];
    const float* dtb   = (const float*)d_in[5];
    float* out = (float*)d_out;
    float* ws  = (float*)d_ws;

    // layout (floats):
    //   xp    : 393216
    //   delta : 4194304
    //   S3    : phase 1: xp_part = 8*393216 = 3145728  [dead after k_prep]
    //           phase 3+: Ec(bf16) | Sc | Hloc(bf16) | Spre | Eg | Sg | Hg
    float* xp      = ws;
    float* delta   = xp + 393216;
    float* S3      = delta + 4194304;
    float* xp_part = S3;

    k_xproj<<<dim3(2048), dim3(NTHR), 0, stream>>>(x, xw, xp_part);
    k_prep <<<dim3(384),  dim3(NTHR), 0, stream>>>(xp_part, xp);
    k_delta<<<dim3(1024), dim3(NTHR), 0, stream>>>(xp, dtw, dtb, delta);

    constexpr int G = 8;
    constexpr int CHv = 64;
    // sizes (floats): Ec = Bb*CHv*Dm*Ns/2, Sc = Bb*CHv*Dm, Hloc = Bb*CHv*Dm*Ns/2,
    //                 Spre = Bb*CHv*Dm, Eg = Bb*G*Dm*Ns, Sg = Bb*G*Dm, Hg = Bb*G*Dm*Ns
    unsigned short* Ec = (unsigned short*)S3;
    float* Sc   = S3 + (size_t)Bb*CHv*Dm*Ns/2;
    unsigned short* Hloc = (unsigned short*)(Sc + (size_t)Bb*CHv*Dm);
    float* Spre = Sc + (size_t)Bb*CHv*Dm + (size_t)Bb*CHv*Dm*Ns/2;
    float* Eg   = Spre + (size_t)Bb*CHv*Dm;
    float* Sg   = Eg   + (size_t)Bb*G*Dm*Ns;
    float* Hg   = Sg   + (size_t)Bb*G*Dm;

    k_scan_part<CHv>  <<<dim3(Bb*CHv*4), dim3(NTHR), 0, stream>>>(delta, x, xp, A_log, Ec, Sc);
    k_comb1<CHv, G>   <<<dim3(Bb*G*Dm*Ns/NTHR), dim3(NTHR), 0, stream>>>(Ec, Sc, A_log, Hloc, Spre, Eg, Sg);
    k_comb2<G>        <<<dim3(Bb*Dm*Ns/NTHR), dim3(NTHR), 0, stream>>>(Eg, Sg, A_log, Hg);
    k_scan_full<CHv,G><<<dim3(Bb*CHv*4), dim3(NTHR), 0, stream>>>(delta, x, xp, A_log, Dp, Hloc, Spre, Hg, out);
}